// Round 16
// baseline (1465.313 us; speedup 1.0000x reference)
//
#include <hip/hip_runtime.h>
#include <hip/hip_fp16.h>

// Problem constants (fixed instance)
#define IHc 128
#define IWc 256
#define OHc 256
#define OWc 512
#define Kc  4
#define Pc  4
#define Bc  4
#define Cc  128

constexpr int Nn  = IHc * IWc;        // 32768 input pixels
constexpr int Ee  = Nn * Kc * Pc;     // 524288 scatter entries
constexpr int Oo  = OHc * OWc;        // 131072 output pixels
constexpr int BC  = Bc * Cc;          // 512 planes
constexpr int NT  = Oo / 64;          // 2048 output tiles (64 px each)
constexpr int TCAP = 384;             // per-tile entry cap (Poisson(256), 8-sigma safe)

typedef float    f32x4 __attribute__((ext_vector_type(4)));
typedef float    f32x2 __attribute__((ext_vector_type(2)));
typedef unsigned u32x4 __attribute__((ext_vector_type(4)));
typedef unsigned u32x2 __attribute__((ext_vector_type(2)));
typedef int      i32x4 __attribute__((ext_vector_type(4)));

static __device__ __forceinline__ unsigned short h_bits(__half h) {
    unsigned short u; __builtin_memcpy(&u, &h, 2); return u;
}
static __device__ __forceinline__ float f_from_hbits(unsigned u) {
    __half h; unsigned short us = (unsigned short)(u & 0xffffu);
    __builtin_memcpy(&h, &us, 2); return __half2float(h);
}
static __device__ __forceinline__ float2 h2_to_f2(unsigned u) {
    __half2 h; __builtin_memcpy(&h, &u, 4); return __half22float2(h);
}

// ---------------- Phase P fused: transpose x -> xT fp16 AND tile-dense fill ----
// Entry list is dense PER 64-PX TILE (t = o>>6): pos = atomicAdd(tcnt[t]),
// ent = {n<<16 | w_fp16, px_in_tile}. Gather can then divide a tile's list
// evenly across lane-groups (perfect balance, no per-pixel quantization).

#define TP 64   // planes per tile
#define TN 256  // n per tile

__global__ __launch_bounds__(256) void prep_kernel(
        const float* __restrict__ x, __half* __restrict__ xt,
        const i32x4* __restrict__ sm2, const f32x2* __restrict__ iw2,
        int* __restrict__ tcnt, u32x2* __restrict__ ents) {
    int tid = threadIdx.x;
    // ---- fill part: 2 entries per thread ----
    int g = (blockIdx.y * gridDim.x + blockIdx.x) * 256 + tid;   // 0..262143
    i32x4 e2 = __builtin_nontemporal_load(&sm2[g]);              // entries 2g, 2g+1
    f32x2 w2 = __builtin_nontemporal_load(&iw2[g]);
    int n = g >> 3;                                              // (2g)>>4 == (2g+1)>>4
    {
        int o = e2.y * OWc + e2.x;
        int t = o >> 6;
        u32x2 ent;
        ent.x = ((unsigned)n << 16) | (unsigned)h_bits(__float2half_rn(w2.x * 0.25f));
        ent.y = (unsigned)(o & 63);
        int pos = atomicAdd(&tcnt[t], 1);
        if (pos < TCAP) ents[(size_t)t * TCAP + pos] = ent;
    }
    {
        int o = e2.w * OWc + e2.z;
        int t = o >> 6;
        u32x2 ent;
        ent.x = ((unsigned)n << 16) | (unsigned)h_bits(__float2half_rn(w2.y * 0.25f));
        ent.y = (unsigned)(o & 63);
        int pos = atomicAdd(&tcnt[t], 1);
        if (pos < TCAP) ents[(size_t)t * TCAP + pos] = ent;
    }

    // ---- transpose part ----
    __shared__ __half lds[TP][TN];        // 32 KB
    int n0 = blockIdx.x * TN;
    int p0 = blockIdx.y * TP;
    #pragma unroll 8
    for (int i = 0; i < TP; ++i) {
        float v = __builtin_nontemporal_load(&x[(size_t)(p0 + i) * Nn + n0 + tid]);
        lds[i][tid] = __float2half_rn(v);
    }
    __syncthreads();
    alignas(16) __half tmp[TP];
    #pragma unroll
    for (int i = 0; i < TP; ++i) tmp[i] = lds[i][tid];   // col read: 2-way bank (free)
    f32x4* dst = (f32x4*)(xt + (size_t)(n0 + tid) * BC + p0);
    const f32x4* src = (const f32x4*)tmp;
    #pragma unroll
    for (int q = 0; q < TP / 8; ++q) dst[q] = src[q];    // 128 B contiguous per thread
}

// ---------------- Phase 1: gather, XCD-pinned slices + balanced dense list ----
// Grid 16384 blocks (512 thr): g = bid & 7 (64-plane slice == XCD round-robin),
// tile tb = bid >> 3 (64 px). Per-XCD xT working set = 4 MB = its L2.
// 64 lane-groups step the tile's dense entry list strided (k = gid + 64j):
// balance is +-1 entry (vs 61% utilization of the per-pixel-bucket loop).
// Accumulation goes straight to LDS via ds_add_f32 (atomicAdd on tbuf) --
// LDS pipe runs parallel to VALU; pitch-68 keeps conflicts ~2-4 way.
// Unroll 2 with both entry-loads issued upfront (chain depth 1 e-load).
// Epilogue: nt full-line stores (proven clean).

#define TPIT 68

__global__ __launch_bounds__(512) void gather14(const u32x4* __restrict__ xt4,
                                                const int* __restrict__ tcnt,
                                                const u32x2* __restrict__ ents,
                                                float* __restrict__ out) {
    __shared__ float tbuf[64][TPIT];     // 17.4 KB

    int tid = threadIdx.x;
    int bid = blockIdx.x;
    int g   = bid & 7;           // plane slice [64g, 64g+64)  == XCD id (heuristic)
    int tb  = bid >> 3;          // output tile (64 px)
    int o0  = tb * 64;

    // zero tbuf (64*68 = 4352 floats = 1088 f32x4)
    {
        f32x4* z = (f32x4*)&tbuf[0][0];
        f32x4 zero = { 0.f, 0.f, 0.f, 0.f };
        for (int i = tid; i < 1088; i += 512) z[i] = zero;
    }
    int Lt = tcnt[tb];
    Lt = (Lt < TCAP) ? Lt : TCAP;
    __syncthreads();

    int gid = tid >> 3;          // lane-group 0..63
    int q   = tid & 7;           // plane-sub: planes [64g+8q, +8)
    const u32x4* __restrict__ xb = xt4 + g * 8 + q;
    const u32x2* __restrict__ eb = ents + (size_t)tb * TCAP;

#define PROC(E)                                                         \
    {                                                                   \
        unsigned lo = (E).x;                                            \
        int px = (int)(E).y;                                            \
        float wf = f_from_hbits(lo);                                    \
        u32x4 r = xb[(size_t)(lo >> 16) * 64];                          \
        float* row = tbuf[px];                                          \
        float2 t0 = h2_to_f2(r.x), t1 = h2_to_f2(r.y);                  \
        float2 t2 = h2_to_f2(r.z), t3 = h2_to_f2(r.w);                  \
        atomicAdd(&row[8 * q + 0], wf * t0.x);                          \
        atomicAdd(&row[8 * q + 1], wf * t0.y);                          \
        atomicAdd(&row[8 * q + 2], wf * t1.x);                          \
        atomicAdd(&row[8 * q + 3], wf * t1.y);                          \
        atomicAdd(&row[8 * q + 4], wf * t2.x);                          \
        atomicAdd(&row[8 * q + 5], wf * t2.y);                          \
        atomicAdd(&row[8 * q + 6], wf * t3.x);                          \
        atomicAdd(&row[8 * q + 7], wf * t3.y);                          \
    }

    for (int k = gid; k < Lt; k += 128) {
        u32x2 ea = eb[k];                       // 8-lane broadcast load
        int kb = k + 64;
        if (kb < Lt) {
            u32x2 eb2 = eb[kb];                 // issued before processing ea
            PROC(ea);
            PROC(eb2);
        } else {
            PROC(ea);
        }
    }
#undef PROC

    __syncthreads();

    // ---- store: thread t -> plane pr = t>>3 (0..63), octant qt = t&7 ----
    // v0: px [4qt, +4), v1: px [32+4qt, +4). Each 8-lane group's v0 (and v1)
    // covers one complete 128 B line (nt full-line pattern, proven clean).
    {
        int pr = tid >> 3;
        int qt = tid & 7;
        float* base = out + (size_t)(64 * g + pr) * Oo + o0;
        int p0x = 4 * qt;
        f32x4 v0 = { tbuf[p0x + 0][pr], tbuf[p0x + 1][pr],
                     tbuf[p0x + 2][pr], tbuf[p0x + 3][pr] };
        f32x4 v1 = { tbuf[32 + p0x + 0][pr], tbuf[32 + p0x + 1][pr],
                     tbuf[32 + p0x + 2][pr], tbuf[32 + p0x + 3][pr] };
        __builtin_nontemporal_store(v0, (f32x4*)(base + p0x));
        __builtin_nontemporal_store(v1, (f32x4*)(base + 32 + p0x));
    }
}

// ---------------- Fallback (ws too small): correct but slow atomic scatter ----------------

__global__ void fallback_scatter(const float* __restrict__ x, const int* __restrict__ sm,
                                 const float* __restrict__ iw, float* __restrict__ out) {
    int e = blockIdx.x * blockDim.x + threadIdx.x;
    if (e >= Ee) return;
    int ox = sm[2 * e + 0];
    int oy = sm[2 * e + 1];
    int o = oy * OWc + ox;
    int n = e >> 4;
    float w = iw[e] * 0.25f;
    for (int p = 0; p < BC; ++p)
        atomicAdd(&out[(size_t)p * Oo + o], x[(size_t)p * Nn + n] * w);
}

// ---------------- launch ----------------

extern "C" void kernel_launch(void* const* d_in, const int* in_sizes, int n_in,
                              void* d_out, int out_size, void* d_ws, size_t ws_size,
                              hipStream_t stream) {
    const float* x  = (const float*)d_in[0];
    const int*   sm = (const int*)d_in[1];
    const float* iw = (const float*)d_in[2];
    float* out = (float*)d_out;

    // ws layout (bytes):
    //   tcnt    : NT*4        = 8192     @ 0
    //   ents    : NT*TCAP*8   = 6291456  @ 8192
    //   xT      : Nn*BC*2     = 33554432 @ 6299648 (16B aligned)
    constexpr size_t WS_NEED = 6299648 + (size_t)Nn * BC * 2;
    if (ws_size < WS_NEED) {
        (void)hipMemsetAsync(d_out, 0, (size_t)out_size * sizeof(float), stream);
        fallback_scatter<<<Ee / 256, 256, 0, stream>>>(x, sm, iw, out);
        return;
    }

    char* ws = (char*)d_ws;
    int*    tcnt = (int*)(ws + 0);
    u32x2*  ents = (u32x2*)(ws + 8192);
    __half* xt   = (__half*)(ws + 6299648);

    (void)hipMemsetAsync(tcnt, 0, NT * sizeof(int), stream);

    dim3 tgrid(Nn / TN, BC / TP);   // (128, 8) = 1024 blocks; 2 entries/thread fill
    prep_kernel<<<tgrid, 256, 0, stream>>>(x, xt, (const i32x4*)sm, (const f32x2*)iw,
                                           tcnt, ents);

    gather14<<<NT * 8, 512, 0, stream>>>((const u32x4*)xt, tcnt, ents, out);
}

// Round 17
// 150.210 us; speedup vs baseline: 9.7551x; 9.7551x over previous
//
#include <hip/hip_runtime.h>
#include <hip/hip_fp16.h>

// Problem constants (fixed instance)
#define IHc 128
#define IWc 256
#define OHc 256
#define OWc 512
#define Kc  4
#define Pc  4
#define Bc  4
#define Cc  128

constexpr int Nn  = IHc * IWc;        // 32768 input pixels
constexpr int Ee  = Nn * Kc * Pc;     // 524288 scatter entries
constexpr int Oo  = OHc * OWc;        // 131072 output pixels
constexpr int BC  = Bc * Cc;          // 512 planes
constexpr int CAP = 24;               // bucket capacity (P(overflow) ~0, clamped)

typedef float    f32x4 __attribute__((ext_vector_type(4)));
typedef float    f32x2 __attribute__((ext_vector_type(2)));
typedef unsigned u32x4 __attribute__((ext_vector_type(4)));
typedef int      i32x4 __attribute__((ext_vector_type(4)));

static __device__ __forceinline__ unsigned short h_bits(__half h) {
    unsigned short u; __builtin_memcpy(&u, &h, 2); return u;
}
static __device__ __forceinline__ float f_from_hbits(unsigned u) {
    __half h; unsigned short us = (unsigned short)(u & 0xffffu);
    __builtin_memcpy(&h, &us, 2); return __half2float(h);
}
static __device__ __forceinline__ float2 h2_to_f2(unsigned u) {
    __half2 h; __builtin_memcpy(&h, &u, 4); return __half22float2(h);
}

// ---------------- Phase P fused: transpose x -> xT fp16 AND bucket-fill CSR ----

#define TP 64   // planes per tile
#define TN 256  // n per tile

__global__ __launch_bounds__(256) void prep_kernel(
        const float* __restrict__ x, __half* __restrict__ xt,
        const i32x4* __restrict__ sm2, const f32x2* __restrict__ iw2,
        int* __restrict__ counts, unsigned* __restrict__ entries) {
    int tid = threadIdx.x;
    // ---- bucket-fill part: 2 entries per thread ----
    int g = (blockIdx.y * gridDim.x + blockIdx.x) * 256 + tid;   // 0..262143
    i32x4 e2 = __builtin_nontemporal_load(&sm2[g]);              // entries 2g, 2g+1
    f32x2 w2 = __builtin_nontemporal_load(&iw2[g]);
    int n = g >> 3;                                              // (2g)>>4 == (2g+1)>>4
    {
        int o = e2.y * OWc + e2.x;
        unsigned ent = ((unsigned)n << 16) |
                       (unsigned)h_bits(__float2half_rn(w2.x * 0.25f));
        int pos = atomicAdd(&counts[o], 1);
        if (pos < CAP) entries[o * CAP + pos] = ent;
    }
    {
        int o = e2.w * OWc + e2.z;
        unsigned ent = ((unsigned)n << 16) |
                       (unsigned)h_bits(__float2half_rn(w2.y * 0.25f));
        int pos = atomicAdd(&counts[o], 1);
        if (pos < CAP) entries[o * CAP + pos] = ent;
    }

    // ---- transpose part ----
    __shared__ __half lds[TP][TN];        // 32 KB
    int n0 = blockIdx.x * TN;
    int p0 = blockIdx.y * TP;
    #pragma unroll 8
    for (int i = 0; i < TP; ++i) {
        float v = __builtin_nontemporal_load(&x[(size_t)(p0 + i) * Nn + n0 + tid]);
        lds[i][tid] = __float2half_rn(v);
    }
    __syncthreads();
    alignas(16) __half tmp[TP];
    #pragma unroll
    for (int i = 0; i < TP; ++i) tmp[i] = lds[i][tid];   // col read: 2-way bank (free)
    f32x4* dst = (f32x4*)(xt + (size_t)(n0 + tid) * BC + p0);
    const f32x4* src = (const f32x4*)tmp;
    #pragma unroll
    for (int q = 0; q < TP / 8; ++q) dst[q] = src[q];    // 128 B contiguous per thread
}

// ---------------- Phase 1: gather, XCD-pinned slices, 128-px tiles ----------
// Grid 8192 blocks (512 thr): g = bid & 7 (64-plane slice == XCD round-robin),
// tile = 128 px. Slot s of wave w owns pixels 16w+s and 16w+8+s (sequential
// loops: summed-pair quantization ~67% util vs 61% single). Entry batch =
// ONE 16 B dwordx4 (8-lane broadcast); 4 independent 128 B xb loads/batch.
// Per block writes 512 B contiguous per plane row (two 256 B half-epilogues).
// Epilogue: nt full-line stores -- proven clean (WRITE=262 MB since R9).

#define TILE_O 128
#define TPIT 68

#define GATHER_PX(acc, cnt, js)                                             \
    for (int j = 0; j < cnt; j += 4) {                                      \
        u32x4 es = *(const u32x4*)(entries + js + j);                       \
        unsigned e0 = es.x;                                                 \
        unsigned e1 = (j + 1 < cnt) ? es.y : 0u;                            \
        unsigned e2 = (j + 2 < cnt) ? es.z : 0u;                            \
        unsigned e3 = (j + 3 < cnt) ? es.w : 0u;                            \
        u32x4 r0 = xb[(size_t)(e0 >> 16) * 64];                             \
        u32x4 r1 = xb[(size_t)(e1 >> 16) * 64];                             \
        u32x4 r2 = xb[(size_t)(e2 >> 16) * 64];                             \
        u32x4 r3 = xb[(size_t)(e3 >> 16) * 64];                             \
        float w0 = f_from_hbits(e0), w1 = f_from_hbits(e1);                 \
        float w2 = f_from_hbits(e2), w3 = f_from_hbits(e3);                 \
        float2 t0, t1;                                                      \
        t0 = h2_to_f2(r0.x); t1 = h2_to_f2(r1.x);                           \
        acc[0] += w0 * t0.x + w1 * t1.x;  acc[1] += w0 * t0.y + w1 * t1.y;  \
        t0 = h2_to_f2(r0.y); t1 = h2_to_f2(r1.y);                           \
        acc[2] += w0 * t0.x + w1 * t1.x;  acc[3] += w0 * t0.y + w1 * t1.y;  \
        t0 = h2_to_f2(r0.z); t1 = h2_to_f2(r1.z);                           \
        acc[4] += w0 * t0.x + w1 * t1.x;  acc[5] += w0 * t0.y + w1 * t1.y;  \
        t0 = h2_to_f2(r0.w); t1 = h2_to_f2(r1.w);                           \
        acc[6] += w0 * t0.x + w1 * t1.x;  acc[7] += w0 * t0.y + w1 * t1.y;  \
        t0 = h2_to_f2(r2.x); t1 = h2_to_f2(r3.x);                           \
        acc[0] += w2 * t0.x + w3 * t1.x;  acc[1] += w2 * t0.y + w3 * t1.y;  \
        t0 = h2_to_f2(r2.y); t1 = h2_to_f2(r3.y);                           \
        acc[2] += w2 * t0.x + w3 * t1.x;  acc[3] += w2 * t0.y + w3 * t1.y;  \
        t0 = h2_to_f2(r2.z); t1 = h2_to_f2(r3.z);                           \
        acc[4] += w2 * t0.x + w3 * t1.x;  acc[5] += w2 * t0.y + w3 * t1.y;  \
        t0 = h2_to_f2(r2.w); t1 = h2_to_f2(r3.w);                           \
        acc[6] += w2 * t0.x + w3 * t1.x;  acc[7] += w2 * t0.y + w3 * t1.y;  \
    }

__global__ __launch_bounds__(512) void gather15(const u32x4* __restrict__ xt4,
                                                const int* __restrict__ counts,
                                                const unsigned* __restrict__ entries,
                                                float* __restrict__ out) {
    __shared__ float tbuf[TILE_O][TPIT];     // 34.8 KB

    int tid = threadIdx.x;
    int bid = blockIdx.x;
    int g    = bid & 7;          // plane slice [64g, 64g+64)  == XCD id (heuristic)
    int o0   = (bid >> 3) * TILE_O;

    int w = tid >> 6;            // wave 0..7 -> px [16w, 16w+16)
    int l = tid & 63;
    int s = l >> 3;              // slot
    int q = l & 7;               // planes [64g+8q, +8)
    const u32x4* __restrict__ xb = xt4 + g * 8 + q;

    int pxA = 16 * w + s;
    int pxB = pxA + 8;
    int oA  = o0 + pxA;
    int oB  = o0 + pxB;
    int cA  = counts[oA];  cA = (cA < CAP) ? cA : CAP;
    int cB  = counts[oB];  cB = (cB < CAP) ? cB : CAP;
    int jsA = oA * CAP;
    int jsB = oB * CAP;

    float accA[8], accB[8];
    #pragma unroll
    for (int i = 0; i < 8; ++i) { accA[i] = 0.f; accB[i] = 0.f; }

    GATHER_PX(accA, cA, jsA)
    GATHER_PX(accB, cB, jsB)

    // ---- stage: lane (w,s,q) -> tbuf[pxA/pxB][8q..8q+8) ----
    {
        float* rowA = tbuf[pxA];
        f32x4 loA = { accA[0], accA[1], accA[2], accA[3] };
        f32x4 hiA = { accA[4], accA[5], accA[6], accA[7] };
        *(f32x4*)(rowA + 8 * q)     = loA;
        *(f32x4*)(rowA + 8 * q + 4) = hiA;
        float* rowB = tbuf[pxB];
        f32x4 loB = { accB[0], accB[1], accB[2], accB[3] };
        f32x4 hiB = { accB[4], accB[5], accB[6], accB[7] };
        *(f32x4*)(rowB + 8 * q)     = loB;
        *(f32x4*)(rowB + 8 * q + 4) = hiB;
    }
    __syncthreads();

    // ---- store: two half-epilogues (R15 pattern); thread t -> plane pr = t>>3,
    // octant qt = t&7; per half: v0 px [4qt,+4), v1 px [32+4qt,+4) -- each
    // 8-lane group's instruction covers one complete 128 B line; the two halves
    // make each block's plane-row 512 B contiguous at HBM.
    {
        int pr = tid >> 3;
        int qt = tid & 7;
        int p0x = 4 * qt;
        float* base = out + (size_t)(64 * g + pr) * Oo + o0;
        #pragma unroll
        for (int h = 0; h < 2; ++h) {
            int off = 64 * h;
            f32x4 v0 = { tbuf[off + p0x + 0][pr], tbuf[off + p0x + 1][pr],
                         tbuf[off + p0x + 2][pr], tbuf[off + p0x + 3][pr] };
            f32x4 v1 = { tbuf[off + 32 + p0x + 0][pr], tbuf[off + 32 + p0x + 1][pr],
                         tbuf[off + 32 + p0x + 2][pr], tbuf[off + 32 + p0x + 3][pr] };
            __builtin_nontemporal_store(v0, (f32x4*)(base + off + p0x));
            __builtin_nontemporal_store(v1, (f32x4*)(base + off + 32 + p0x));
        }
    }
}

// ---------------- Fallback (ws too small): correct but slow atomic scatter ----------------

__global__ void fallback_scatter(const float* __restrict__ x, const int* __restrict__ sm,
                                 const float* __restrict__ iw, float* __restrict__ out) {
    int e = blockIdx.x * blockDim.x + threadIdx.x;
    if (e >= Ee) return;
    int ox = sm[2 * e + 0];
    int oy = sm[2 * e + 1];
    int o = oy * OWc + ox;
    int n = e >> 4;
    float w = iw[e] * 0.25f;
    for (int p = 0; p < BC; ++p)
        atomicAdd(&out[(size_t)p * Oo + o], x[(size_t)p * Nn + n] * w);
}

// ---------------- launch ----------------

extern "C" void kernel_launch(void* const* d_in, const int* in_sizes, int n_in,
                              void* d_out, int out_size, void* d_ws, size_t ws_size,
                              hipStream_t stream) {
    const float* x  = (const float*)d_in[0];
    const int*   sm = (const int*)d_in[1];
    const float* iw = (const float*)d_in[2];
    float* out = (float*)d_out;

    // ws layout (bytes):
    //   counts  : Oo*4       = 524288   @ 0        (pad to 524800)
    //   entries : Oo*CAP*4   = 12582912 @ 524800
    //   xT      : Nn*BC*2    = 33554432 @ 13107712 (16B aligned)
    constexpr size_t WS_NEED = 13107712 + (size_t)Nn * BC * 2;
    if (ws_size < WS_NEED) {
        (void)hipMemsetAsync(d_out, 0, (size_t)out_size * sizeof(float), stream);
        fallback_scatter<<<Ee / 256, 256, 0, stream>>>(x, sm, iw, out);
        return;
    }

    char* ws = (char*)d_ws;
    int*      counts  = (int*)(ws + 0);
    unsigned* entries = (unsigned*)(ws + 524800);
    __half*   xt      = (__half*)(ws + 13107712);

    (void)hipMemsetAsync(counts, 0, Oo * sizeof(int), stream);

    dim3 tgrid(Nn / TN, BC / TP);   // (128, 8) = 1024 blocks; 2 entries/thread bucket-fill
    prep_kernel<<<tgrid, 256, 0, stream>>>(x, xt, (const i32x4*)sm, (const f32x2*)iw,
                                           counts, entries);

    gather15<<<(Oo / TILE_O) * 8, 512, 0, stream>>>((const u32x4*)xt, counts, entries, out);
}

// Round 18
// 146.980 us; speedup vs baseline: 9.9694x; 1.0220x over previous
//
#include <hip/hip_runtime.h>
#include <hip/hip_fp16.h>

// Problem constants (fixed instance)
#define IHc 128
#define IWc 256
#define OHc 256
#define OWc 512
#define Kc  4
#define Pc  4
#define Bc  4
#define Cc  128

constexpr int Nn  = IHc * IWc;        // 32768 input pixels
constexpr int Ee  = Nn * Kc * Pc;     // 524288 scatter entries
constexpr int Oo  = OHc * OWc;        // 131072 output pixels
constexpr int BC  = Bc * Cc;          // 512 planes
constexpr int CAP = 24;               // bucket capacity (P(overflow) ~1e-12/px, clamped)

typedef float    f32x4 __attribute__((ext_vector_type(4)));
typedef float    f32x2 __attribute__((ext_vector_type(2)));
typedef unsigned u32x4 __attribute__((ext_vector_type(4)));
typedef int      i32x4 __attribute__((ext_vector_type(4)));

static __device__ __forceinline__ unsigned short h_bits(__half h) {
    unsigned short u; __builtin_memcpy(&u, &h, 2); return u;
}
static __device__ __forceinline__ float f_from_hbits(unsigned u) {
    __half h; unsigned short us = (unsigned short)(u & 0xffffu);
    __builtin_memcpy(&h, &us, 2); return __half2float(h);
}
static __device__ __forceinline__ float2 h2_to_f2(unsigned u) {
    __half2 h; __builtin_memcpy(&h, &u, 4); return __half22float2(h);
}

// ---------------- Phase P fused: transpose x -> xT fp16 AND bucket-fill CSR ----

#define TP 64   // planes per tile
#define TN 256  // n per tile

__global__ __launch_bounds__(256) void prep_kernel(
        const float* __restrict__ x, __half* __restrict__ xt,
        const i32x4* __restrict__ sm2, const f32x2* __restrict__ iw2,
        int* __restrict__ counts, unsigned* __restrict__ entries) {
    int tid = threadIdx.x;
    // ---- bucket-fill part: 2 entries per thread ----
    int g = (blockIdx.y * gridDim.x + blockIdx.x) * 256 + tid;   // 0..262143
    i32x4 e2 = __builtin_nontemporal_load(&sm2[g]);              // entries 2g, 2g+1
    f32x2 w2 = __builtin_nontemporal_load(&iw2[g]);
    int n = g >> 3;                                              // (2g)>>4 == (2g+1)>>4
    {
        int o = e2.y * OWc + e2.x;
        unsigned ent = ((unsigned)n << 16) |
                       (unsigned)h_bits(__float2half_rn(w2.x * 0.25f));
        int pos = atomicAdd(&counts[o], 1);
        if (pos < CAP) entries[o * CAP + pos] = ent;
    }
    {
        int o = e2.w * OWc + e2.z;
        unsigned ent = ((unsigned)n << 16) |
                       (unsigned)h_bits(__float2half_rn(w2.y * 0.25f));
        int pos = atomicAdd(&counts[o], 1);
        if (pos < CAP) entries[o * CAP + pos] = ent;
    }

    // ---- transpose part ----
    __shared__ __half lds[TP][TN];        // 32 KB
    int n0 = blockIdx.x * TN;
    int p0 = blockIdx.y * TP;
    #pragma unroll 8
    for (int i = 0; i < TP; ++i) {
        float v = __builtin_nontemporal_load(&x[(size_t)(p0 + i) * Nn + n0 + tid]);
        lds[i][tid] = __float2half_rn(v);
    }
    __syncthreads();
    alignas(16) __half tmp[TP];
    #pragma unroll
    for (int i = 0; i < TP; ++i) tmp[i] = lds[i][tid];   // col read: 2-way bank (free)
    f32x4* dst = (f32x4*)(xt + (size_t)(n0 + tid) * BC + p0);
    const f32x4* src = (const f32x4*)tmp;
    #pragma unroll
    for (int q = 0; q < TP / 8; ++q) dst[q] = src[q];    // 128 B contiguous per thread
}

// ---------------- Phase 1: gather, XCD-pinned slices, 512-thr blocks ----------
// Grid 16384 blocks: g = bid & 7 (64-plane slice == XCD via round-robin),
// o0 = (bid>>3)*64 (64-px tile). Per-XCD xT working set = 4 MB = its L2.
// Each x4 batch of entries is ONE 16 B-aligned dwordx4 (8 lanes/group read
// same addr -> L1 broadcast); chain = 1 e-load -> 4 independent xb loads.
// counts read per-lane direct. Only the epilogue barrier remains.
// Epilogue: tbuf transpose; nt stores -- each 8-lane group's instruction
// covers one complete 128 B line (proven-clean write pattern).

#define TILE_O 64
#define TPIT 68

__global__ __launch_bounds__(512) void gather13(const u32x4* __restrict__ xt4,
                                                const int* __restrict__ counts,
                                                const unsigned* __restrict__ entries,
                                                float* __restrict__ out) {
    __shared__ float tbuf[TILE_O][TPIT];     // 17.4 KB

    int tid = threadIdx.x;
    int bid = blockIdx.x;
    int g    = bid & 7;          // plane slice [64g, 64g+64)  == XCD id (heuristic)
    int o0   = (bid >> 3) * TILE_O;

    int w = tid >> 6;            // wave 0..7 -> px [8w, 8w+8)
    int l = tid & 63;
    int s = l >> 3;              // slot -> pixel 8w+s
    int q = l & 7;               // planes [64g+8q, +8)
    const u32x4* __restrict__ xb = xt4 + g * 8 + q;

    int px  = 8 * w + s;
    int opx = o0 + px;
    int c   = counts[opx];                   // broadcast within group
    int cnt = (c < CAP) ? c : CAP;
    int js  = opx * CAP;

    float acc[8];
    #pragma unroll
    for (int i = 0; i < 8; ++i) acc[i] = 0.f;

    for (int j = 0; j < cnt; j += 4) {       // j <= 20: batch stays inside bucket
        u32x4 es = *(const u32x4*)(entries + js + j);
        unsigned e0 = es.x;
        unsigned e1 = (j + 1 < cnt) ? es.y : 0u;   // sentinel: row 0, w=0
        unsigned e2 = (j + 2 < cnt) ? es.z : 0u;
        unsigned e3 = (j + 3 < cnt) ? es.w : 0u;
        u32x4 r0 = xb[(size_t)(e0 >> 16) * 64];
        u32x4 r1 = xb[(size_t)(e1 >> 16) * 64];
        u32x4 r2 = xb[(size_t)(e2 >> 16) * 64];
        u32x4 r3 = xb[(size_t)(e3 >> 16) * 64];
        float w0 = f_from_hbits(e0), w1 = f_from_hbits(e1);
        float w2 = f_from_hbits(e2), w3 = f_from_hbits(e3);
        float2 t0, t1;
        t0 = h2_to_f2(r0.x); t1 = h2_to_f2(r1.x);
        acc[0] += w0 * t0.x + w1 * t1.x;  acc[1] += w0 * t0.y + w1 * t1.y;
        t0 = h2_to_f2(r0.y); t1 = h2_to_f2(r1.y);
        acc[2] += w0 * t0.x + w1 * t1.x;  acc[3] += w0 * t0.y + w1 * t1.y;
        t0 = h2_to_f2(r0.z); t1 = h2_to_f2(r1.z);
        acc[4] += w0 * t0.x + w1 * t1.x;  acc[5] += w0 * t0.y + w1 * t1.y;
        t0 = h2_to_f2(r0.w); t1 = h2_to_f2(r1.w);
        acc[6] += w0 * t0.x + w1 * t1.x;  acc[7] += w0 * t0.y + w1 * t1.y;
        t0 = h2_to_f2(r2.x); t1 = h2_to_f2(r3.x);
        acc[0] += w2 * t0.x + w3 * t1.x;  acc[1] += w2 * t0.y + w3 * t1.y;
        t0 = h2_to_f2(r2.y); t1 = h2_to_f2(r3.y);
        acc[2] += w2 * t0.x + w3 * t1.x;  acc[3] += w2 * t0.y + w3 * t1.y;
        t0 = h2_to_f2(r2.z); t1 = h2_to_f2(r3.z);
        acc[4] += w2 * t0.x + w3 * t1.x;  acc[5] += w2 * t0.y + w3 * t1.y;
        t0 = h2_to_f2(r2.w); t1 = h2_to_f2(r3.w);
        acc[6] += w2 * t0.x + w3 * t1.x;  acc[7] += w2 * t0.y + w3 * t1.y;
    }

    // ---- stage: lane (w,s,q) -> tbuf[px][8q..8q+8) (two f32x4) ----
    {
        f32x4 lo = { acc[0], acc[1], acc[2], acc[3] };
        f32x4 hi = { acc[4], acc[5], acc[6], acc[7] };
        float* row = tbuf[px];
        *(f32x4*)(row + 8 * q)     = lo;
        *(f32x4*)(row + 8 * q + 4) = hi;
    }
    __syncthreads();

    // ---- store: thread t -> plane pr = t>>3 (0..63), octant qt = t&7 ----
    // v0: px [4qt, +4), v1: px [32+4qt, +4). Each 8-lane group's v0 (and v1)
    // covers one complete 128 B line.
    {
        int pr = tid >> 3;
        int qt = tid & 7;
        float* base = out + (size_t)(64 * g + pr) * Oo + o0;
        int p0x = 4 * qt;
        f32x4 v0 = { tbuf[p0x + 0][pr], tbuf[p0x + 1][pr],
                     tbuf[p0x + 2][pr], tbuf[p0x + 3][pr] };
        f32x4 v1 = { tbuf[32 + p0x + 0][pr], tbuf[32 + p0x + 1][pr],
                     tbuf[32 + p0x + 2][pr], tbuf[32 + p0x + 3][pr] };
        __builtin_nontemporal_store(v0, (f32x4*)(base + p0x));
        __builtin_nontemporal_store(v1, (f32x4*)(base + 32 + p0x));
    }
}

// ---------------- Fallback (ws too small): correct but slow atomic scatter ----------------

__global__ void fallback_scatter(const float* __restrict__ x, const int* __restrict__ sm,
                                 const float* __restrict__ iw, float* __restrict__ out) {
    int e = blockIdx.x * blockDim.x + threadIdx.x;
    if (e >= Ee) return;
    int ox = sm[2 * e + 0];
    int oy = sm[2 * e + 1];
    int o = oy * OWc + ox;
    int n = e >> 4;
    float w = iw[e] * 0.25f;
    for (int p = 0; p < BC; ++p)
        atomicAdd(&out[(size_t)p * Oo + o], x[(size_t)p * Nn + n] * w);
}

// ---------------- launch ----------------

extern "C" void kernel_launch(void* const* d_in, const int* in_sizes, int n_in,
                              void* d_out, int out_size, void* d_ws, size_t ws_size,
                              hipStream_t stream) {
    const float* x  = (const float*)d_in[0];
    const int*   sm = (const int*)d_in[1];
    const float* iw = (const float*)d_in[2];
    float* out = (float*)d_out;

    // ws layout (bytes):
    //   counts  : Oo*4       = 524288   @ 0        (pad to 524800)
    //   entries : Oo*CAP*4   = 12582912 @ 524800
    //   xT      : Nn*BC*2    = 33554432 @ 13107712 (16B aligned)
    constexpr size_t WS_NEED = 13107712 + (size_t)Nn * BC * 2;
    if (ws_size < WS_NEED) {
        (void)hipMemsetAsync(d_out, 0, (size_t)out_size * sizeof(float), stream);
        fallback_scatter<<<Ee / 256, 256, 0, stream>>>(x, sm, iw, out);
        return;
    }

    char* ws = (char*)d_ws;
    int*      counts  = (int*)(ws + 0);
    unsigned* entries = (unsigned*)(ws + 524800);
    __half*   xt      = (__half*)(ws + 13107712);

    (void)hipMemsetAsync(counts, 0, Oo * sizeof(int), stream);

    dim3 tgrid(Nn / TN, BC / TP);   // (128, 8) = 1024 blocks; 2 entries/thread bucket-fill
    prep_kernel<<<tgrid, 256, 0, stream>>>(x, xt, (const i32x4*)sm, (const f32x2*)iw,
                                           counts, entries);

    gather13<<<(Oo / TILE_O) * 8, 512, 0, stream>>>((const u32x4*)xt, counts, entries, out);
}